// Round 4
// baseline (1125.013 us; speedup 1.0000x reference)
//
#include <hip/hip_runtime.h>
#include <hip/hip_bf16.h>
#include <stdint.h>

typedef __hip_bfloat16 bf16;
typedef float v4f __attribute__((ext_vector_type(4)));
typedef short v8s __attribute__((ext_vector_type(8)));

#define DEV __device__ __forceinline__

DEV float b2f(bf16 x) { return __bfloat162float(x); }
DEV bf16 f2b(float x) { return __float2bfloat16(x); }

// dtype-polymorphic loaders/stores (global <-> f32 registers)
DEV void load4(const float* p, float* f) {
  float4 t = *(const float4*)p;
  f[0] = t.x; f[1] = t.y; f[2] = t.z; f[3] = t.w;
}
DEV void load4(const bf16* p, float* f) {
  union { uint2 u; bf16 h[4]; } t;
  t.u = *(const uint2*)p;
#pragma unroll
  for (int i = 0; i < 4; i++) f[i] = b2f(t.h[i]);
}
DEV void load8(const float* p, float* f) {
  float4 a = ((const float4*)p)[0], b = ((const float4*)p)[1];
  f[0] = a.x; f[1] = a.y; f[2] = a.z; f[3] = a.w;
  f[4] = b.x; f[5] = b.y; f[6] = b.z; f[7] = b.w;
}
DEV void load8(const bf16* p, float* f) {
  union { uint4 u; bf16 h[8]; } t;
  t.u = *(const uint4*)p;
#pragma unroll
  for (int i = 0; i < 8; i++) f[i] = b2f(t.h[i]);
}
DEV void store4(bf16* p, const float* f) {
  union { uint2 u; bf16 h[4]; } t;
#pragma unroll
  for (int i = 0; i < 4; i++) t.h[i] = f2b(f[i]);
  *(uint2*)p = t.u;
}
DEV void store4(float* p, const float* f) {
  *(float4*)p = make_float4(f[0], f[1], f[2], f[3]);
}

// async global->LDS, 16B per lane. LDS dest = wave-uniform base + lane*16.
DEV void gld_lds16(const bf16* g, bf16* l) {
  auto gp = reinterpret_cast<const __attribute__((address_space(1))) uint32_t*>(
      reinterpret_cast<uintptr_t>(g));
  auto lp = reinterpret_cast<__attribute__((address_space(3))) uint32_t*>(
      reinterpret_cast<uintptr_t>(l));
  __builtin_amdgcn_global_load_lds(gp, lp, 16, 0, 0);
}

// ------------------------------------------------------------------
// LayerNorm over 2048 columns. One block (256 thr) per row.
// ------------------------------------------------------------------
template <typename XT>
__global__ __launch_bounds__(256)
void ln2048_kernel(const XT* __restrict__ x, const float* __restrict__ w,
                   const float* __restrict__ b, bf16* __restrict__ y) {
  const int N = 2048;
  int row = blockIdx.x, tid = threadIdx.x;
  const XT* xr = x + (size_t)row * N;
  bf16* yr = y + (size_t)row * N;
  float f[8], s = 0.f, ss = 0.f;
  load8(xr + tid * 8, f);
#pragma unroll
  for (int i = 0; i < 8; i++) { s += f[i]; ss += f[i] * f[i]; }
#pragma unroll
  for (int off = 32; off >= 1; off >>= 1) {
    s  += __shfl_xor(s, off, 64);
    ss += __shfl_xor(ss, off, 64);
  }
  __shared__ float red0[4], red1[4];
  int wv = tid >> 6;
  if ((tid & 63) == 0) { red0[wv] = s; red1[wv] = ss; }
  __syncthreads();
  s  = red0[0] + red0[1] + red0[2] + red0[3];
  ss = red1[0] + red1[1] + red1[2] + red1[3];
  float mean = s * (1.f / N);
  float var  = ss * (1.f / N) - mean * mean;
  float inv  = rsqrtf(var + 1e-5f);
  float wf[8], bf_[8];
  load8(w + tid * 8, wf);
  load8(b + tid * 8, bf_);
  union { uint4 u; bf16 h[8]; } vo;
#pragma unroll
  for (int i = 0; i < 8; i++)
    vo.h[i] = f2b((f[i] - mean) * inv * wf[i] + bf_[i]);
  ((uint4*)yr)[tid] = vo.u;
}

// ------------------------------------------------------------------
// Per-head LayerNorm (DH=128) + RoPE, in place on bf16 q/k.
// ------------------------------------------------------------------
__global__ __launch_bounds__(256)
void headln_rope_kernel(bf16* __restrict__ q, const float* __restrict__ w,
                        const float* __restrict__ b, const float* __restrict__ fcos,
                        const float* __restrict__ fsin) {
  int tid = threadIdx.x;
  int wv = tid >> 6, ln = tid & 63;
  int idx = blockIdx.x * 4 + wv;
  int row = idx >> 4, h = idx & 15;
  int srow = row & 2047;
  bf16* p = q + (size_t)row * 2048 + h * 128 + ln * 2;
  union { unsigned int u; bf16 h2[2]; } v;
  v.u = *(const unsigned int*)p;
  float x0 = b2f(v.h2[0]), x1 = b2f(v.h2[1]);
  float s = x0 + x1, ss = x0 * x0 + x1 * x1;
#pragma unroll
  for (int off = 32; off >= 1; off >>= 1) {
    s  += __shfl_xor(s, off, 64);
    ss += __shfl_xor(ss, off, 64);
  }
  float mean = s * (1.f / 128.f);
  float var  = ss * (1.f / 128.f) - mean * mean;
  float inv  = rsqrtf(var + 1e-5f);
  float w0 = w[ln * 2], w1 = w[ln * 2 + 1];
  float b0 = b[ln * 2], b1 = b[ln * 2 + 1];
  x0 = (x0 - mean) * inv * w0 + b0;
  x1 = (x1 - mean) * inv * w1 + b1;
  float c  = fcos[srow * 64 + ln];
  float sn = fsin[srow * 64 + ln];
  v.h2[0] = f2b(x0 * c - x1 * sn);
  v.h2[1] = f2b(x0 * sn + x1 * c);
  *(unsigned int*)p = v.u;
}

// ------------------------------------------------------------------
// Weight convert+transpose: src f32 [K][N] -> dst bf16 [N][K].
// ------------------------------------------------------------------
__global__ __launch_bounds__(256)
void convT_kernel(const float* __restrict__ src, bf16* __restrict__ dst,
                  int K, int N) {
  __shared__ float T[64][65];
  int n0 = blockIdx.x * 64, k0 = blockIdx.y * 64;
  int t = threadIdx.x;
  int tr = t >> 4, tc4 = (t & 15) * 4;
#pragma unroll
  for (int it = 0; it < 4; it++) {
    float4 v = *(const float4*)&src[(size_t)(k0 + tr + 16 * it) * N + n0 + tc4];
    T[tr + 16 * it][tc4 + 0] = v.x;
    T[tr + 16 * it][tc4 + 1] = v.y;
    T[tr + 16 * it][tc4 + 2] = v.z;
    T[tr + 16 * it][tc4 + 3] = v.w;
  }
  __syncthreads();
#pragma unroll
  for (int it = 0; it < 4; it++) {
    int n = tr + 16 * it;
    union { uint2 u; bf16 h[4]; } o;
#pragma unroll
    for (int c = 0; c < 4; c++) o.h[c] = f2b(T[tc4 + c][n]);
    *(uint2*)&dst[(size_t)(n0 + n) * K + k0 + tc4] = o.u;
  }
}

// ------------------------------------------------------------------
// MFMA bt-GEMM (m97 structure): C = A * BT^T.
// R4: + bijective XCD-chunk swizzle on the flattened grid (T1), and
// segmented epilogue addressing so one launch can write q/k/v:
//   C[(n>>ldc_log2)*seg_stride + (m<<ldc_log2) + (n&(ldc-1))]
// (non-fused callers pass ldc_log2 = log2(N), seg_stride = 0).
// ------------------------------------------------------------------
template <int EPI, typename RT, typename OT>
__global__ __launch_bounds__(256, 2)
void mfma_gemm_kernel(const bf16* __restrict__ A, const bf16* __restrict__ BT,
                      OT* __restrict__ C, const float* __restrict__ bias,
                      const RT* __restrict__ res, int M, int N, int K,
                      int ldc_log2, size_t seg_stride) {
  __shared__ __align__(16) bf16 As[128 * 32];
  __shared__ __align__(16) bf16 Bs[128 * 32];
  int tid = threadIdx.x;
  int lane = tid & 63, wave = tid >> 6;
  int wr = wave >> 1, wc = wave & 1;

  // XCD swizzle (all grids have nwg % 8 == 0)
  int nbx = gridDim.x;
  int bid = blockIdx.y * nbx + blockIdx.x;
  int nwg = nbx * gridDim.y;
  int cpx = nwg >> 3;
  int swz = (bid & 7) * cpx + (bid >> 3);
  int m0 = (swz / nbx) * 128, n0 = (swz % nbx) * 128;

  int ls_row = lane >> 2;          // 0..15
  int ls_k   = (lane & 3) * 8;     // 0,8,16,24
  int t0 = 2 * wave, t1 = 2 * wave + 1;
  const bf16* gA0 = A  + (size_t)(m0 + 16 * t0 + ls_row) * K + ls_k;
  const bf16* gA1 = A  + (size_t)(m0 + 16 * t1 + ls_row) * K + ls_k;
  const bf16* gB0 = BT + (size_t)(n0 + 16 * t0 + ls_row) * K + ls_k;
  const bf16* gB1 = BT + (size_t)(n0 + 16 * t1 + ls_row) * K + ls_k;
  bf16* lA0 = As + t0 * 512;
  bf16* lA1 = As + t1 * 512;
  bf16* lB0 = Bs + t0 * 512;
  bf16* lB1 = Bs + t1 * 512;

  int fr = lane & 15, fk = (lane >> 4) * 8;
  const bf16* pA = As + (wr * 64 + fr) * 32 + fk;
  const bf16* pB = Bs + (wc * 64 + fr) * 32 + fk;

  v4f acc[4][4];
#pragma unroll
  for (int i = 0; i < 4; i++)
#pragma unroll
    for (int j = 0; j < 4; j++) acc[i][j] = (v4f){0.f, 0.f, 0.f, 0.f};

  for (int k0 = 0; k0 < K; k0 += 32) {
    __syncthreads();
    gld_lds16(gA0, lA0); gld_lds16(gA1, lA1);
    gld_lds16(gB0, lB0); gld_lds16(gB1, lB1);
    gA0 += 32; gA1 += 32; gB0 += 32; gB1 += 32;
    __syncthreads();
    v8s af[4], bfr[4];
#pragma unroll
    for (int i = 0; i < 4; i++) af[i]  = *(const v8s*)(pA + i * 16 * 32);
#pragma unroll
    for (int j = 0; j < 4; j++) bfr[j] = *(const v8s*)(pB + j * 16 * 32);
#pragma unroll
    for (int i = 0; i < 4; i++)
#pragma unroll
      for (int j = 0; j < 4; j++)
        acc[i][j] = __builtin_amdgcn_mfma_f32_16x16x32_bf16(af[i], bfr[j],
                                                            acc[i][j], 0, 0, 0);
  }

  int rq = (lane >> 4) * 4;
  int ldm = 1 << ldc_log2;
#pragma unroll
  for (int j = 0; j < 4; j++) {
    int n = n0 + wc * 64 + j * 16 + (lane & 15);
    float bb = (EPI >= 1) ? bias[n] : 0.f;
    size_t cseg = (size_t)(n >> ldc_log2) * seg_stride + (n & (ldm - 1));
#pragma unroll
    for (int i = 0; i < 4; i++) {
#pragma unroll
      for (int r = 0; r < 4; r++) {
        int m = m0 + wr * 64 + i * 16 + rq + r;
        float val = acc[i][j][r] + bb;
        if (EPI == 2)
          val = 0.5f * val * (1.f + erff(val * 0.70710678118654752f));
        if (EPI == 1) {
          if constexpr (__is_same(RT, float)) val += res[(size_t)m * N + n];
          else                                val += b2f(res[(size_t)m * N + n]);
        }
        size_t cix = cseg + ((size_t)m << ldc_log2);
        if constexpr (__is_same(OT, float)) C[cix] = val;
        else                                C[cix] = f2b(val);
      }
    }
  }
}

// ------------------------------------------------------------------
// Fallback vector GEMM (round-3 proven path, used if ws too small).
// ------------------------------------------------------------------
template <int EPI, typename RT, typename OT>
__global__ __launch_bounds__(256)
void gemm_kernel(const bf16* __restrict__ A, const float* __restrict__ Bm,
                 OT* __restrict__ C, const float* __restrict__ bias,
                 const RT* __restrict__ res, int M, int N, int K) {
  const int BK = 32;
  __shared__ __align__(16) float As[BK][68];
  __shared__ __align__(16) float Bs[BK][68];
  int tid = threadIdx.x;
  int bm = blockIdx.y, bn = blockIdx.x;
  int tx = tid & 15, ty = tid >> 4;
  int am = tid >> 2, ak8 = (tid & 3) * 8;
  int bkr = tid >> 3, bn8 = (tid & 7) * 8;
  const bf16* Aptr = A + (size_t)(bm * 64 + am) * K + ak8;
  const float* Bptr = Bm + (size_t)bkr * N + bn * 64 + bn8;
  float acc[4][4] = {};
  for (int k0 = 0; k0 < K; k0 += BK) {
    float av[8], bv[8];
    load8(Aptr, av);
    load8(Bptr, bv);
    __syncthreads();
#pragma unroll
    for (int j = 0; j < 8; j++) As[ak8 + j][am] = av[j];
#pragma unroll
    for (int j = 0; j < 8; j++) Bs[bkr][bn8 + j] = bv[j];
    __syncthreads();
    Aptr += BK;
    Bptr += (size_t)BK * N;
#pragma unroll 8
    for (int kk = 0; kk < BK; kk++) {
      float a0[4], b0[4];
      *(float4*)a0 = *(const float4*)&As[kk][ty * 4];
      *(float4*)b0 = *(const float4*)&Bs[kk][tx * 4];
#pragma unroll
      for (int i = 0; i < 4; i++)
#pragma unroll
        for (int j = 0; j < 4; j++)
          acc[i][j] += a0[i] * b0[j];
    }
  }
  int m0 = bm * 64 + ty * 4, n0 = bn * 64 + tx * 4;
#pragma unroll
  for (int i = 0; i < 4; i++) {
    float r4[4];
#pragma unroll
    for (int j = 0; j < 4; j++) r4[j] = acc[i][j];
    if (EPI >= 1) {
      float bb[4];
      load4(bias + n0, bb);
#pragma unroll
      for (int j = 0; j < 4; j++) r4[j] += bb[j];
    }
    if (EPI == 2) {
#pragma unroll
      for (int j = 0; j < 4; j++)
        r4[j] = 0.5f * r4[j] * (1.f + erff(r4[j] * 0.70710678118654752f));
    }
    if (EPI == 1) {
      float rr[4];
      load4(res + (size_t)(m0 + i) * N + n0, rr);
#pragma unroll
      for (int j = 0; j < 4; j++) r4[j] += rr[j];
    }
    store4(&C[(size_t)(m0 + i) * N + n0], r4);
  }
}

// ------------------------------------------------------------------
// MFMA flash-style attention, PIPELINED, QBLK=128 (R4).
// 256 thr = 4 waves (2x2), Q-tile 128, KV-tile 64, DH=128.
// Same verified pipeline skeleton as R3's passing kernel (K dbuf in
// LDS via gld_lds ping-pong, V prefetched to regs, 2 barriers/tile,
// static 2-tile unroll) with doubled Q state: staging bytes and
// barriers per FLOP halve, 64 MFMA per tile per wave.
// Per-wave: Q rows wr*64..+64 (4 row-frags), S cols wc*32..+32,
// O cols wc*64..+64. LDS: K 2x16K + Vt 16K + P[128][64] 16K +
// Lp[2][128] 1K = 65KB -> 2 blocks/CU. VGPR ~220 (<256, 2 w/SIMD).
// ------------------------------------------------------------------
#define VSWZ(r) (((((r) >> 3) ^ (r)) & 7) << 4)

__global__ __launch_bounds__(256, 2)
void attn_kernel(const bf16* __restrict__ q, const bf16* __restrict__ k,
                 const bf16* __restrict__ v, bf16* __restrict__ o) {
  const int S = 2048, HD = 2048;
  __shared__ __align__(16) char smem[66560];
  char* Ks0 = smem;                    // K ping [64][128]bf16 (prologue: Q rows 0-63)
  char* Ks1 = smem + 16384;            // K pong              (prologue: Q rows 64-127)
  char* VtB = smem + 32768;            // V^T [128][64]bf16
  char* PB  = smem + 49152;            // P [128][64]bf16
  float* Lp = (float*)(smem + 65536);  // [2][128]

  // bijective XCD-chunk swizzle: 512 blocks, 8 XCDs, 64 each.
  int id = blockIdx.x;
  int swzb = (id & 7) * 64 + (id >> 3);
  int bh = swzb >> 4, qb = swzb & 15;
  int q0 = qb * 128;
  size_t base = (size_t)(bh >> 4) * S * HD + (size_t)(bh & 15) * 128;

  int tid = threadIdx.x;
  int lane = tid & 63, wave = tid >> 6;
  int wr = wave >> 1, wc = wave & 1;
  int fr = lane & 15, fg = lane >> 4;

  Lp[tid] = 0.f;  // 256 entries, 256 threads

  union V4U { uint4 u; bf16 h[8]; };
  int vr0 = (tid & 15) * 4, vd0 = (tid >> 4) * 8;

  // ---- prologue: Q (128x128) -> Ks0+Ks1, V tile0 -> regs ----
#pragma unroll
  for (int t = 0; t < 8; t++) {
    int ti = wave * 8 + t;           // 0..31, 4 rows each
    int r = ti * 4 + fg;             // Q row 0..127
    int cb = (fr * 16) ^ ((r & 7) << 4);
    bf16* dst = (bf16*)(ti < 16 ? Ks0 : Ks1) + (ti & 15) * 512;
    gld_lds16(q + base + (size_t)(q0 + r) * HD + (cb >> 1), dst);
  }
  V4U vA[4], vB[4];
#pragma unroll
  for (int j = 0; j < 4; j++)
    vA[j].u = *(const uint4*)&v[base + (size_t)(vr0 + j) * HD + vd0];
  __syncthreads();  // Q staged

  v8s qfrag[4][4];
  {
    const char* qbuf = wr ? Ks1 : Ks0;
#pragma unroll
    for (int i = 0; i < 4; i++)
#pragma unroll
      for (int kk = 0; kk < 4; kk++) {
        int rb = i * 16 + fr;        // row within buffer, 0..63
        int off = rb * 256 + ((kk * 64 + fg * 16) ^ ((rb & 7) << 4));
        qfrag[i][kk] = *(const v8s*)(qbuf + off);
      }
  }
  __syncthreads();  // all Q reads done before K0 overwrites Ks0

  // stage K tile0 -> Ks0
#pragma unroll
  for (int t = 0; t < 4; t++) {
    int ti = wave * 4 + t;
    int r = ti * 4 + fg;
    int cb = (fr * 16) ^ ((r & 7) << 4);
    gld_lds16(k + base + (size_t)r * HD + (cb >> 1), (bf16*)Ks0 + ti * 512);
  }
  __syncthreads();  // K0 drained (syncthreads waits vmcnt 0)

  v4f oacc[4][4];
#pragma unroll
  for (int i = 0; i < 4; i++)
#pragma unroll
    for (int j = 0; j < 4; j++) oacc[i][j] = (v4f){0.f, 0.f, 0.f, 0.f};

  const float scale = 0.08838834764831845f;

  // Per-tile body. Hazards: Vt/PB writes vs reads separated by the mid
  // barrier; KNXT staging targets the buffer last read before the
  // previous body's end barrier; end barrier drains vmcnt.
#define ATTN_TILE(KT, KCUR, KNXT, VCUR, VNXT, STAGE_NEXT)                     \
  {                                                                           \
    _Pragma("unroll")                                                         \
    for (int c = 0; c < 8; c++) {                                             \
      int d = vd0 + c;                                                        \
      union { uint2 u2; bf16 hh[4]; } pk;                                     \
      _Pragma("unroll")                                                       \
      for (int j = 0; j < 4; j++) pk.hh[j] = VCUR[j].h[c];                    \
      *(uint2*)(VtB + d * 128 + ((vr0 * 2) ^ VSWZ(d))) = pk.u2;               \
    }                                                                         \
    if (STAGE_NEXT) {                                                         \
      _Pragma("unroll")                                                       \
      for (int t = 0; t < 4; t++) {                                           \
        int ti = wave * 4 + t;                                                \
        int r = ti * 4 + fg;                                                  \
        int cb = (fr * 16) ^ ((r & 7) << 4);                                  \
        gld_lds16(k + base + (size_t)((KT) + 64 + r) * HD + (cb >> 1),        \
                  (bf16*)(KNXT) + ti * 512);                                  \
      }                                                                       \
      _Pragma("unroll")                                                       \
      for (int j = 0; j < 4; j++)                                             \
        VNXT[j].u =                                                           \
            *(const uint4*)&v[base + (size_t)((KT) + 64 + vr0 + j) * HD + vd0]; \
    }                                                                         \
    v4f sacc[4][2];                                                           \
    _Pragma("unroll")                                                         \
    for (int i = 0; i < 4; i++)                                               \
      _Pragma("unroll")                                                       \
      for (int j = 0; j < 2; j++) sacc[i][j] = (v4f){0.f, 0.f, 0.f, 0.f};     \
    __builtin_amdgcn_s_setprio(1);                                            \
    _Pragma("unroll")                                                         \
    for (int kk = 0; kk < 4; kk++) {                                          \
      v8s kf[2];                                                              \
      _Pragma("unroll")                                                       \
      for (int j = 0; j < 2; j++) {                                           \
        int row = wc * 32 + j * 16 + fr;                                      \
        int off = row * 256 + ((kk * 64 + fg * 16) ^ ((row & 7) << 4));       \
        kf[j] = *(const v8s*)((KCUR) + off);                                  \
      }                                                                       \
      _Pragma("unroll")                                                       \
      for (int i = 0; i < 4; i++)                                             \
        _Pragma("unroll")                                                     \
        for (int j = 0; j < 2; j++)                                           \
          sacc[i][j] = __builtin_amdgcn_mfma_f32_16x16x32_bf16(               \
              qfrag[i][kk], kf[j], sacc[i][j], 0, 0, 0);                      \
    }                                                                         \
    __builtin_amdgcn_s_setprio(0);                                            \
    _Pragma("unroll")                                                         \
    for (int i = 0; i < 4; i++)                                               \
      _Pragma("unroll")                                                       \
      for (int r = 0; r < 4; r++) {                                           \
        int qrow = wr * 64 + i * 16 + fg * 4 + r;                             \
        float e0 = __expf(sacc[i][0][r] * scale);                             \
        float e1 = __expf(sacc[i][1][r] * scale);                             \
        int sw = VSWZ(qrow);                                                  \
        int c0 = wc * 64 + fr * 2;                                            \
        *(bf16*)(PB + qrow * 128 + (c0 ^ sw)) = f2b(e0);                      \
        *(bf16*)(PB + qrow * 128 + ((c0 + 32) ^ sw)) = f2b(e1);               \
        float s_ = e0 + e1;                                                   \
        s_ += __shfl_xor(s_, 1, 64);                                          \
        s_ += __shfl_xor(s_, 2, 64);                                          \
        s_ += __shfl_xor(s_, 4, 64);                                          \
        s_ += __shfl_xor(s_, 8, 64);                                          \
        if (fr == 0) Lp[wc * 128 + qrow] += s_;                               \
      }                                                                       \
    __syncthreads();                                                          \
    __builtin_amdgcn_s_setprio(1);                                            \
    _Pragma("unroll")                                                         \
    for (int kk2 = 0; kk2 < 2; kk2++) {                                       \
      v8s pf[4], vf[4];                                                       \
      _Pragma("unroll")                                                       \
      for (int i = 0; i < 4; i++) {                                           \
        int row = wr * 64 + i * 16 + fr;                                      \
        int off = row * 128 + ((kk2 * 64 + fg * 16) ^ VSWZ(row));             \
        pf[i] = *(const v8s*)(PB + off);                                      \
      }                                                                       \
      _Pragma("unroll")                                                       \
      for (int j = 0; j < 4; j++) {                                           \
        int row = wc * 64 + j * 16 + fr;                                      \
        int off = row * 128 + ((kk2 * 64 + fg * 16) ^ VSWZ(row));             \
        vf[j] = *(const v8s*)(VtB + off);                                     \
      }                                                                       \
      _Pragma("unroll")                                                       \
      for (int i = 0; i < 4; i++)                                             \
        _Pragma("unroll")                                                     \
        for (int j = 0; j < 4; j++)                                           \
          oacc[i][j] = __builtin_amdgcn_mfma_f32_16x16x32_bf16(               \
              pf[i], vf[j], oacc[i][j], 0, 0, 0);                             \
    }                                                                         \
    __builtin_amdgcn_s_setprio(0);                                            \
    __syncthreads();                                                          \
  }

  for (int tp = 0; tp < 16; tp++) {
    int kt = tp * 128;
    ATTN_TILE(kt, Ks0, Ks1, vA, vB, true);
    ATTN_TILE(kt + 64, Ks1, Ks0, vB, vA, (tp < 15));
  }
#undef ATTN_TILE

  // ---- normalize + store ----
#pragma unroll
  for (int i = 0; i < 4; i++)
#pragma unroll
    for (int r = 0; r < 4; r++) {
      int qrow = wr * 64 + i * 16 + fg * 4 + r;
      float linv = 1.f / (Lp[qrow] + Lp[128 + qrow]);
#pragma unroll
      for (int j = 0; j < 4; j++) {
        int d = wc * 64 + j * 16 + fr;
        o[base + (size_t)(q0 + qrow) * HD + d] = f2b(oacc[i][j][r] * linv);
      }
    }
}

// ------------------------------------------------------------------
// Orchestration. Inputs f32, output f32, intermediates bf16.
// ------------------------------------------------------------------
extern "C" void kernel_launch(void* const* d_in, const int* in_sizes, int n_in,
                              void* d_out, int out_size, void* d_ws, size_t ws_size,
                              hipStream_t stream) {
  (void)in_sizes; (void)n_in; (void)out_size;
  const float* x    = (const float*)d_in[0];
  const float* fcos = (const float*)d_in[1];
  const float* fsin = (const float*)d_in[2];
  const float* wq   = (const float*)d_in[3];
  const float* wk   = (const float*)d_in[4];
  const float* wv   = (const float*)d_in[5];
  const float* nqw  = (const float*)d_in[6];
  const float* nqb  = (const float*)d_in[7];
  const float* nkw  = (const float*)d_in[8];
  const float* nkb  = (const float*)d_in[9];
  const float* wo   = (const float*)d_in[10];
  const float* bo   = (const float*)d_in[11];
  const float* ln1w = (const float*)d_in[12];
  const float* ln1b = (const float*)d_in[13];
  const float* ln3w = (const float*)d_in[14];
  const float* ln3b = (const float*)d_in[15];
  const float* w1   = (const float*)d_in[16];
  const float* b1   = (const float*)d_in[17];
  const float* w2   = (const float*)d_in[18];
  const float* b2   = (const float*)d_in[19];
  float* out = (float*)d_out;

  const size_t SEG = (size_t)4096 * 2048;  // 8M bf16 = 16 MB
  bf16* base = (bf16*)d_ws;
  bf16* q        = base + 0 * SEG;
  bf16* k        = base + 1 * SEG;
  bf16* v        = base + 2 * SEG;
  bf16* n1       = base + 3 * SEG;
  bf16* attn_out = base + 3 * SEG;
  bf16* x2       = base + 4 * SEG;
  bf16* n3       = base + 5 * SEG;
  bf16* h        = base + 0 * SEG;  // 64MB overlays q/k/v/attn_out

  dim3 blk(256);
  ln2048_kernel<float><<<4096, blk, 0, stream>>>(x, ln1w, ln1b, n1);

  bool mfma_path = ws_size >= (size_t)128 * 1024 * 1024;
  if (mfma_path) {
    bf16* W = base + 6 * SEG;            // 32MB weight area
    bf16* wqT = W;                       // wq/wk/wvT contiguous -> fused BT
    bf16* wkT = W + 4 * 1024 * 1024;
    bf16* wvT = W + 8 * 1024 * 1024;
    bf16* woT = W;
    bf16* w1T = W;
    bf16* w2T = W;

    dim3 cg22(32, 32);
    dim3 g16(16, 32);
    dim3 g48(48, 32);                    // fused QKV: N=6144
    dim3 g64(64, 32);

    convT_kernel<<<cg22, blk, 0, stream>>>(wq, wqT, 2048, 2048);
    convT_kernel<<<cg22, blk, 0, stream>>>(wk, wkT, 2048, 2048);
    convT_kernel<<<cg22, blk, 0, stream>>>(wv, wvT, 2048, 2048);
    // fused QKV: BT rows 0-2047 = wqT, 2048-4095 = wkT, 4096-6143 = wvT;
    // output segment n>>11 selects q/k/v (SEG-strided, contiguous).
    mfma_gemm_kernel<0, float, bf16><<<g48, blk, 0, stream>>>(n1, wqT, q, nullptr, nullptr, 4096, 6144, 2048, 11, SEG);
    headln_rope_kernel<<<16384, blk, 0, stream>>>(q, nqw, nqb, fcos, fsin);
    headln_rope_kernel<<<16384, blk, 0, stream>>>(k, nkw, nkb, fcos, fsin);
    attn_kernel<<<512, blk, 0, stream>>>(q, k, v, attn_out);
    convT_kernel<<<cg22, blk, 0, stream>>>(wo, woT, 2048, 2048);
    mfma_gemm_kernel<1, float, bf16><<<g16, blk, 0, stream>>>(attn_out, woT, x2, bo, x, 4096, 2048, 2048, 11, 0);
    ln2048_kernel<bf16><<<4096, blk, 0, stream>>>(x2, ln3w, ln3b, n3);
    convT_kernel<<<dim3(128, 32), blk, 0, stream>>>(w1, w1T, 2048, 8192);
    mfma_gemm_kernel<2, float, bf16><<<g64, blk, 0, stream>>>(n3, w1T, h, b1, nullptr, 4096, 8192, 2048, 13, 0);
    convT_kernel<<<dim3(32, 128), blk, 0, stream>>>(w2, w2T, 8192, 2048);
    mfma_gemm_kernel<1, bf16, float><<<g16, blk, 0, stream>>>(h, w2T, out, b2, x2, 4096, 2048, 8192, 11, 0);
  } else {
    dim3 g2048(32, 64), g8192(128, 64);
    gemm_kernel<0, float, bf16><<<g2048, blk, 0, stream>>>(n1, wq, q, nullptr, nullptr, 4096, 2048, 2048);
    gemm_kernel<0, float, bf16><<<g2048, blk, 0, stream>>>(n1, wk, k, nullptr, nullptr, 4096, 2048, 2048);
    gemm_kernel<0, float, bf16><<<g2048, blk, 0, stream>>>(n1, wv, v, nullptr, nullptr, 4096, 2048, 2048);
    headln_rope_kernel<<<16384, blk, 0, stream>>>(q, nqw, nqb, fcos, fsin);
    headln_rope_kernel<<<16384, blk, 0, stream>>>(k, nkw, nkb, fcos, fsin);
    attn_kernel<<<512, blk, 0, stream>>>(q, k, v, attn_out);
    gemm_kernel<1, float, bf16><<<g2048, blk, 0, stream>>>(attn_out, wo, x2, bo, x, 4096, 2048, 2048);
    ln2048_kernel<bf16><<<4096, blk, 0, stream>>>(x2, ln3w, ln3b, n3);
    gemm_kernel<2, float, bf16><<<g8192, blk, 0, stream>>>(n3, w1, h, b1, nullptr, 4096, 8192, 2048);
    gemm_kernel<1, bf16, float><<<g2048, blk, 0, stream>>>(h, w2, out, b2, x2, 4096, 2048, 8192);
  }
}

// Round 5
// 1017.658 us; speedup vs baseline: 1.1055x; 1.1055x over previous
//
#include <hip/hip_runtime.h>
#include <hip/hip_bf16.h>
#include <stdint.h>

typedef __hip_bfloat16 bf16;
typedef float v4f __attribute__((ext_vector_type(4)));
typedef short v8s __attribute__((ext_vector_type(8)));

#define DEV __device__ __forceinline__

DEV float b2f(bf16 x) { return __bfloat162float(x); }
DEV bf16 f2b(float x) { return __float2bfloat16(x); }

// dtype-polymorphic loaders/stores (global <-> f32 registers)
DEV void load4(const float* p, float* f) {
  float4 t = *(const float4*)p;
  f[0] = t.x; f[1] = t.y; f[2] = t.z; f[3] = t.w;
}
DEV void load4(const bf16* p, float* f) {
  union { uint2 u; bf16 h[4]; } t;
  t.u = *(const uint2*)p;
#pragma unroll
  for (int i = 0; i < 4; i++) f[i] = b2f(t.h[i]);
}
DEV void load8(const float* p, float* f) {
  float4 a = ((const float4*)p)[0], b = ((const float4*)p)[1];
  f[0] = a.x; f[1] = a.y; f[2] = a.z; f[3] = a.w;
  f[4] = b.x; f[5] = b.y; f[6] = b.z; f[7] = b.w;
}
DEV void load8(const bf16* p, float* f) {
  union { uint4 u; bf16 h[8]; } t;
  t.u = *(const uint4*)p;
#pragma unroll
  for (int i = 0; i < 8; i++) f[i] = b2f(t.h[i]);
}
DEV void store4(bf16* p, const float* f) {
  union { uint2 u; bf16 h[4]; } t;
#pragma unroll
  for (int i = 0; i < 4; i++) t.h[i] = f2b(f[i]);
  *(uint2*)p = t.u;
}
DEV void store4(float* p, const float* f) {
  *(float4*)p = make_float4(f[0], f[1], f[2], f[3]);
}

// async global->LDS, 16B per lane. LDS dest = wave-uniform base + lane*16.
DEV void gld_lds16(const bf16* g, bf16* l) {
  auto gp = reinterpret_cast<const __attribute__((address_space(1))) uint32_t*>(
      reinterpret_cast<uintptr_t>(g));
  auto lp = reinterpret_cast<__attribute__((address_space(3))) uint32_t*>(
      reinterpret_cast<uintptr_t>(l));
  __builtin_amdgcn_global_load_lds(gp, lp, 16, 0, 0);
}

// ------------------------------------------------------------------
// LayerNorm over 2048 columns. One block (256 thr) per row.
// ------------------------------------------------------------------
template <typename XT>
__global__ __launch_bounds__(256)
void ln2048_kernel(const XT* __restrict__ x, const float* __restrict__ w,
                   const float* __restrict__ b, bf16* __restrict__ y) {
  const int N = 2048;
  int row = blockIdx.x, tid = threadIdx.x;
  const XT* xr = x + (size_t)row * N;
  bf16* yr = y + (size_t)row * N;
  float f[8], s = 0.f, ss = 0.f;
  load8(xr + tid * 8, f);
#pragma unroll
  for (int i = 0; i < 8; i++) { s += f[i]; ss += f[i] * f[i]; }
#pragma unroll
  for (int off = 32; off >= 1; off >>= 1) {
    s  += __shfl_xor(s, off, 64);
    ss += __shfl_xor(ss, off, 64);
  }
  __shared__ float red0[4], red1[4];
  int wv = tid >> 6;
  if ((tid & 63) == 0) { red0[wv] = s; red1[wv] = ss; }
  __syncthreads();
  s  = red0[0] + red0[1] + red0[2] + red0[3];
  ss = red1[0] + red1[1] + red1[2] + red1[3];
  float mean = s * (1.f / N);
  float var  = ss * (1.f / N) - mean * mean;
  float inv  = rsqrtf(var + 1e-5f);
  float wf[8], bf_[8];
  load8(w + tid * 8, wf);
  load8(b + tid * 8, bf_);
  union { uint4 u; bf16 h[8]; } vo;
#pragma unroll
  for (int i = 0; i < 8; i++)
    vo.h[i] = f2b((f[i] - mean) * inv * wf[i] + bf_[i]);
  ((uint4*)yr)[tid] = vo.u;
}

// ------------------------------------------------------------------
// Per-head LayerNorm (DH=128) + RoPE, in place on bf16 q AND k in one
// launch (grid 32768: first half q/nq*, second half k/nk*).
// ------------------------------------------------------------------
__global__ __launch_bounds__(256)
void headln_rope_kernel(bf16* __restrict__ qb, bf16* __restrict__ kb,
                        const float* __restrict__ nqw, const float* __restrict__ nqb,
                        const float* __restrict__ nkw, const float* __restrict__ nkb,
                        const float* __restrict__ fcos, const float* __restrict__ fsin) {
  int bid = blockIdx.x;
  bf16* qk; const float* w; const float* b;
  if (bid < 16384) { qk = qb; w = nqw; b = nqb; }
  else             { qk = kb; w = nkw; b = nkb; bid -= 16384; }
  int tid = threadIdx.x;
  int wv = tid >> 6, ln = tid & 63;
  int idx = bid * 4 + wv;
  int row = idx >> 4, h = idx & 15;
  int srow = row & 2047;
  bf16* p = qk + (size_t)row * 2048 + h * 128 + ln * 2;
  union { unsigned int u; bf16 h2[2]; } v;
  v.u = *(const unsigned int*)p;
  float x0 = b2f(v.h2[0]), x1 = b2f(v.h2[1]);
  float s = x0 + x1, ss = x0 * x0 + x1 * x1;
#pragma unroll
  for (int off = 32; off >= 1; off >>= 1) {
    s  += __shfl_xor(s, off, 64);
    ss += __shfl_xor(ss, off, 64);
  }
  float mean = s * (1.f / 128.f);
  float var  = ss * (1.f / 128.f) - mean * mean;
  float inv  = rsqrtf(var + 1e-5f);
  float w0 = w[ln * 2], w1 = w[ln * 2 + 1];
  float b0 = b[ln * 2], b1 = b[ln * 2 + 1];
  x0 = (x0 - mean) * inv * w0 + b0;
  x1 = (x1 - mean) * inv * w1 + b1;
  float c  = fcos[srow * 64 + ln];
  float sn = fsin[srow * 64 + ln];
  v.h2[0] = f2b(x0 * c - x1 * sn);
  v.h2[1] = f2b(x0 * sn + x1 * c);
  *(unsigned int*)p = v.u;
}

// ------------------------------------------------------------------
// Weight convert+transpose: src f32 [K][N] -> dst bf16 [N][K].
// ------------------------------------------------------------------
__global__ __launch_bounds__(256)
void convT_kernel(const float* __restrict__ src, bf16* __restrict__ dst,
                  int K, int N) {
  __shared__ float T[64][65];
  int n0 = blockIdx.x * 64, k0 = blockIdx.y * 64;
  int t = threadIdx.x;
  int tr = t >> 4, tc4 = (t & 15) * 4;
#pragma unroll
  for (int it = 0; it < 4; it++) {
    float4 v = *(const float4*)&src[(size_t)(k0 + tr + 16 * it) * N + n0 + tc4];
    T[tr + 16 * it][tc4 + 0] = v.x;
    T[tr + 16 * it][tc4 + 1] = v.y;
    T[tr + 16 * it][tc4 + 2] = v.z;
    T[tr + 16 * it][tc4 + 3] = v.w;
  }
  __syncthreads();
#pragma unroll
  for (int it = 0; it < 4; it++) {
    int n = tr + 16 * it;
    union { uint2 u; bf16 h[4]; } o;
#pragma unroll
    for (int c = 0; c < 4; c++) o.h[c] = f2b(T[tc4 + c][n]);
    *(uint2*)&dst[(size_t)(n0 + n) * K + k0 + tc4] = o.u;
  }
}

// ------------------------------------------------------------------
// MFMA bt-GEMM (m97 structure): C = A * BT^T.
// Bijective XCD-chunk swizzle on the flattened grid (T1); segmented
// epilogue addressing so one launch can write q/k/v:
//   C[(n>>ldc_log2)*seg_stride + (m<<ldc_log2) + (n&(ldc-1))]
// ------------------------------------------------------------------
template <int EPI, typename RT, typename OT>
__global__ __launch_bounds__(256, 2)
void mfma_gemm_kernel(const bf16* __restrict__ A, const bf16* __restrict__ BT,
                      OT* __restrict__ C, const float* __restrict__ bias,
                      const RT* __restrict__ res, int M, int N, int K,
                      int ldc_log2, size_t seg_stride) {
  __shared__ __align__(16) bf16 As[128 * 32];
  __shared__ __align__(16) bf16 Bs[128 * 32];
  int tid = threadIdx.x;
  int lane = tid & 63, wave = tid >> 6;
  int wr = wave >> 1, wc = wave & 1;

  // XCD swizzle (all grids have nwg % 8 == 0)
  int nbx = gridDim.x;
  int bid = blockIdx.y * nbx + blockIdx.x;
  int nwg = nbx * gridDim.y;
  int cpx = nwg >> 3;
  int swz = (bid & 7) * cpx + (bid >> 3);
  int m0 = (swz / nbx) * 128, n0 = (swz % nbx) * 128;

  int ls_row = lane >> 2;          // 0..15
  int ls_k   = (lane & 3) * 8;     // 0,8,16,24
  int t0 = 2 * wave, t1 = 2 * wave + 1;
  const bf16* gA0 = A  + (size_t)(m0 + 16 * t0 + ls_row) * K + ls_k;
  const bf16* gA1 = A  + (size_t)(m0 + 16 * t1 + ls_row) * K + ls_k;
  const bf16* gB0 = BT + (size_t)(n0 + 16 * t0 + ls_row) * K + ls_k;
  const bf16* gB1 = BT + (size_t)(n0 + 16 * t1 + ls_row) * K + ls_k;
  bf16* lA0 = As + t0 * 512;
  bf16* lA1 = As + t1 * 512;
  bf16* lB0 = Bs + t0 * 512;
  bf16* lB1 = Bs + t1 * 512;

  int fr = lane & 15, fk = (lane >> 4) * 8;
  const bf16* pA = As + (wr * 64 + fr) * 32 + fk;
  const bf16* pB = Bs + (wc * 64 + fr) * 32 + fk;

  v4f acc[4][4];
#pragma unroll
  for (int i = 0; i < 4; i++)
#pragma unroll
    for (int j = 0; j < 4; j++) acc[i][j] = (v4f){0.f, 0.f, 0.f, 0.f};

  for (int k0 = 0; k0 < K; k0 += 32) {
    __syncthreads();
    gld_lds16(gA0, lA0); gld_lds16(gA1, lA1);
    gld_lds16(gB0, lB0); gld_lds16(gB1, lB1);
    gA0 += 32; gA1 += 32; gB0 += 32; gB1 += 32;
    __syncthreads();
    v8s af[4], bfr[4];
#pragma unroll
    for (int i = 0; i < 4; i++) af[i]  = *(const v8s*)(pA + i * 16 * 32);
#pragma unroll
    for (int j = 0; j < 4; j++) bfr[j] = *(const v8s*)(pB + j * 16 * 32);
#pragma unroll
    for (int i = 0; i < 4; i++)
#pragma unroll
      for (int j = 0; j < 4; j++)
        acc[i][j] = __builtin_amdgcn_mfma_f32_16x16x32_bf16(af[i], bfr[j],
                                                            acc[i][j], 0, 0, 0);
  }

  int rq = (lane >> 4) * 4;
  int ldm = 1 << ldc_log2;
#pragma unroll
  for (int j = 0; j < 4; j++) {
    int n = n0 + wc * 64 + j * 16 + (lane & 15);
    float bb = (EPI >= 1) ? bias[n] : 0.f;
    size_t cseg = (size_t)(n >> ldc_log2) * seg_stride + (n & (ldm - 1));
#pragma unroll
    for (int i = 0; i < 4; i++) {
#pragma unroll
      for (int r = 0; r < 4; r++) {
        int m = m0 + wr * 64 + i * 16 + rq + r;
        float val = acc[i][j][r] + bb;
        if (EPI == 2)
          val = 0.5f * val * (1.f + erff(val * 0.70710678118654752f));
        if (EPI == 1) {
          if constexpr (__is_same(RT, float)) val += res[(size_t)m * N + n];
          else                                val += b2f(res[(size_t)m * N + n]);
        }
        size_t cix = cseg + ((size_t)m << ldc_log2);
        if constexpr (__is_same(OT, float)) C[cix] = val;
        else                                C[cix] = f2b(val);
      }
    }
  }
}

// ------------------------------------------------------------------
// Fallback vector GEMM (round-3 proven path, used if ws too small).
// ------------------------------------------------------------------
template <int EPI, typename RT, typename OT>
__global__ __launch_bounds__(256)
void gemm_kernel(const bf16* __restrict__ A, const float* __restrict__ Bm,
                 OT* __restrict__ C, const float* __restrict__ bias,
                 const RT* __restrict__ res, int M, int N, int K) {
  const int BK = 32;
  __shared__ __align__(16) float As[BK][68];
  __shared__ __align__(16) float Bs[BK][68];
  int tid = threadIdx.x;
  int bm = blockIdx.y, bn = blockIdx.x;
  int tx = tid & 15, ty = tid >> 4;
  int am = tid >> 2, ak8 = (tid & 3) * 8;
  int bkr = tid >> 3, bn8 = (tid & 7) * 8;
  const bf16* Aptr = A + (size_t)(bm * 64 + am) * K + ak8;
  const float* Bptr = Bm + (size_t)bkr * N + bn * 64 + bn8;
  float acc[4][4] = {};
  for (int k0 = 0; k0 < K; k0 += BK) {
    float av[8], bv[8];
    load8(Aptr, av);
    load8(Bptr, bv);
    __syncthreads();
#pragma unroll
    for (int j = 0; j < 8; j++) As[ak8 + j][am] = av[j];
#pragma unroll
    for (int j = 0; j < 8; j++) Bs[bkr][bn8 + j] = bv[j];
    __syncthreads();
    Aptr += BK;
    Bptr += (size_t)BK * N;
#pragma unroll 8
    for (int kk = 0; kk < BK; kk++) {
      float a0[4], b0[4];
      *(float4*)a0 = *(const float4*)&As[kk][ty * 4];
      *(float4*)b0 = *(const float4*)&Bs[kk][tx * 4];
#pragma unroll
      for (int i = 0; i < 4; i++)
#pragma unroll
        for (int j = 0; j < 4; j++)
          acc[i][j] += a0[i] * b0[j];
    }
  }
  int m0 = bm * 64 + ty * 4, n0 = bn * 64 + tx * 4;
#pragma unroll
  for (int i = 0; i < 4; i++) {
    float r4[4];
#pragma unroll
    for (int j = 0; j < 4; j++) r4[j] = acc[i][j];
    if (EPI >= 1) {
      float bb[4];
      load4(bias + n0, bb);
#pragma unroll
      for (int j = 0; j < 4; j++) r4[j] += bb[j];
    }
    if (EPI == 2) {
#pragma unroll
      for (int j = 0; j < 4; j++)
        r4[j] = 0.5f * r4[j] * (1.f + erff(r4[j] * 0.70710678118654752f));
    }
    if (EPI == 1) {
      float rr[4];
      load4(res + (size_t)(m0 + i) * N + n0, rr);
#pragma unroll
      for (int j = 0; j < 4; j++) r4[j] += rr[j];
    }
    store4(&C[(size_t)(m0 + i) * N + n0], r4);
  }
}

// ------------------------------------------------------------------
// MFMA flash-style attention, PIPELINED (R3-verified version, QBLK=64).
// 256 thr = 4 waves (2x2), Q-tile 64, KV-tile 64, DH=128.
// K double-buffered in LDS (gld_lds ping-pong), V prefetched to regs
// (T14 issue-early/write-late), both issued BEFORE QK^T so the L2
// latency hides under QK^T+softmax. 2 barriers/tile, statically
// unrolled 2-tile body. R4's QBLK=128 spilled (~160 persistent VGPRs,
// WRITE_SIZE 16->49MB scratch) and regressed 282us — reverted.
// LDS: K 2x16K + Vt 16K + P 8K + Lp 0.5K = 56.5KB -> 2 blocks/CU.
// ------------------------------------------------------------------
#define VSWZ(r) (((((r) >> 3) ^ (r)) & 7) << 4)

__global__ __launch_bounds__(256, 2)
void attn_kernel(const bf16* __restrict__ q, const bf16* __restrict__ k,
                 const bf16* __restrict__ v, bf16* __restrict__ o) {
  const int S = 2048, HD = 2048;
  __shared__ __align__(16) char smem[57856];
  char* Ks0 = smem;                    // K ping [64][128]bf16, 256B rows
  char* Ks1 = smem + 16384;            // K pong
  char* VtB = smem + 32768;            // V^T [128][64]bf16, 128B rows
  char* PB  = smem + 49152;            // P [64][64]bf16, 128B rows
  float* Lp = (float*)(smem + 57344);  // [2][64]

  // bijective XCD-chunk swizzle: 1024 blocks, 8 XCDs, 128 each.
  int id = blockIdx.x;
  int swzb = (id & 7) * 128 + (id >> 3);
  int bh = swzb >> 5, qb = swzb & 31;
  int q0 = qb * 64;
  size_t base = (size_t)(bh >> 4) * S * HD + (size_t)(bh & 15) * 128;

  int tid = threadIdx.x;
  int lane = tid & 63, wave = tid >> 6;
  int wr = wave >> 1, wc = wave & 1;
  int fr = lane & 15, fg = lane >> 4;

  if (tid < 128) Lp[tid] = 0.f;

  union V4U { uint4 u; bf16 h[8]; };
  int vr0 = (tid & 15) * 4, vd0 = (tid >> 4) * 8;

  // ---- prologue: Q -> Ks0, K tile0 -> Ks1, V tile0 -> regs ----
#pragma unroll
  for (int t = 0; t < 4; t++) {
    int ti = wave * 4 + t;
    int r = ti * 4 + fg;
    int cb = (fr * 16) ^ ((r & 7) << 4);
    gld_lds16(q + base + (size_t)(q0 + r) * HD + (cb >> 1), (bf16*)Ks0 + ti * 512);
    gld_lds16(k + base + (size_t)r * HD + (cb >> 1), (bf16*)Ks1 + ti * 512);
  }
  V4U vA[4], vB[4];
#pragma unroll
  for (int j = 0; j < 4; j++)
    vA[j].u = *(const uint4*)&v[base + (size_t)(vr0 + j) * HD + vd0];
  __syncthreads();  // Q + K0 in LDS, V0 in regs

  v8s qfrag[2][4];
#pragma unroll
  for (int i = 0; i < 2; i++)
#pragma unroll
    for (int kk = 0; kk < 4; kk++) {
      int row = wr * 32 + i * 16 + fr;
      int off = row * 256 + ((kk * 64 + fg * 16) ^ ((row & 7) << 4));
      qfrag[i][kk] = *(const v8s*)(Ks0 + off);
    }
  __syncthreads();  // all waves done reading Q before tile0 stages into Ks0

  v4f oacc[2][4];
#pragma unroll
  for (int i = 0; i < 2; i++)
#pragma unroll
    for (int j = 0; j < 4; j++) oacc[i][j] = (v4f){0.f, 0.f, 0.f, 0.f};

  const float scale = 0.08838834764831845f;

  // Per-tile body. Hazards: (a) Vt write guarded by prev tile's end
  // barrier; (b) KNXT staging guarded by prev tile's barriers (last
  // reader was QK^T of tile t-1); V regs drained by the mid barrier.
#define ATTN_TILE(KT, KCUR, KNXT, VCUR, VNXT, STAGE_NEXT)                     \
  {                                                                           \
    _Pragma("unroll")                                                         \
    for (int c = 0; c < 8; c++) {                                             \
      int d = vd0 + c;                                                        \
      union { uint2 u2; bf16 hh[4]; } pk;                                     \
      _Pragma("unroll")                                                       \
      for (int j = 0; j < 4; j++) pk.hh[j] = VCUR[j].h[c];                    \
      *(uint2*)(VtB + d * 128 + ((vr0 * 2) ^ VSWZ(d))) = pk.u2;               \
    }                                                                         \
    if (STAGE_NEXT) {                                                         \
      _Pragma("unroll")                                                       \
      for (int t = 0; t < 4; t++) {                                           \
        int ti = wave * 4 + t;                                                \
        int r = ti * 4 + fg;                                                  \
        int cb = (fr * 16) ^ ((r & 7) << 4);                                  \
        gld_lds16(k + base + (size_t)((KT) + 64 + r) * HD + (cb >> 1),        \
                  (bf16*)(KNXT) + ti * 512);                                  \
      }                                                                       \
      _Pragma("unroll")                                                       \
      for (int j = 0; j < 4; j++)                                             \
        VNXT[j].u =                                                           \
            *(const uint4*)&v[base + (size_t)((KT) + 64 + vr0 + j) * HD + vd0]; \
    }                                                                         \
    v4f sacc[2][2];                                                           \
    _Pragma("unroll")                                                         \
    for (int i = 0; i < 2; i++)                                               \
      _Pragma("unroll")                                                       \
      for (int j = 0; j < 2; j++) sacc[i][j] = (v4f){0.f, 0.f, 0.f, 0.f};     \
    __builtin_amdgcn_s_setprio(1);                                            \
    _Pragma("unroll")                                                         \
    for (int kk = 0; kk < 4; kk++) {                                          \
      v8s kf[2];                                                              \
      _Pragma("unroll")                                                       \
      for (int j = 0; j < 2; j++) {                                           \
        int row = wc * 32 + j * 16 + fr;                                      \
        int off = row * 256 + ((kk * 64 + fg * 16) ^ ((row & 7) << 4));       \
        kf[j] = *(const v8s*)((KCUR) + off);                                  \
      }                                                                       \
      _Pragma("unroll")                                                       \
      for (int i = 0; i < 2; i++)                                             \
        _Pragma("unroll")                                                     \
        for (int j = 0; j < 2; j++)                                           \
          sacc[i][j] = __builtin_amdgcn_mfma_f32_16x16x32_bf16(               \
              qfrag[i][kk], kf[j], sacc[i][j], 0, 0, 0);                      \
    }                                                                         \
    __builtin_amdgcn_s_setprio(0);                                            \
    _Pragma("unroll")                                                         \
    for (int i = 0; i < 2; i++)                                               \
      _Pragma("unroll")                                                       \
      for (int r = 0; r < 4; r++) {                                           \
        int qrow = wr * 32 + i * 16 + fg * 4 + r;                             \
        float e0 = __expf(sacc[i][0][r] * scale);                             \
        float e1 = __expf(sacc[i][1][r] * scale);                             \
        int sw = VSWZ(qrow);                                                  \
        int c0 = wc * 64 + fr * 2;                                            \
        *(bf16*)(PB + qrow * 128 + (c0 ^ sw)) = f2b(e0);                      \
        *(bf16*)(PB + qrow * 128 + ((c0 + 32) ^ sw)) = f2b(e1);               \
        float s_ = e0 + e1;                                                   \
        s_ += __shfl_xor(s_, 1, 64);                                          \
        s_ += __shfl_xor(s_, 2, 64);                                          \
        s_ += __shfl_xor(s_, 4, 64);                                          \
        s_ += __shfl_xor(s_, 8, 64);                                          \
        if (fr == 0) Lp[wc * 64 + qrow] += s_;                                \
      }                                                                       \
    __syncthreads();                                                          \
    __builtin_amdgcn_s_setprio(1);                                            \
    _Pragma("unroll")                                                         \
    for (int kk2 = 0; kk2 < 2; kk2++) {                                       \
      v8s pf[2], vf[4];                                                       \
      _Pragma("unroll")                                                       \
      for (int i = 0; i < 2; i++) {                                           \
        int row = wr * 32 + i * 16 + fr;                                      \
        int off = row * 128 + ((kk2 * 64 + fg * 16) ^ VSWZ(row));             \
        pf[i] = *(const v8s*)(PB + off);                                      \
      }                                                                       \
      _Pragma("unroll")                                                       \
      for (int j = 0; j < 4; j++) {                                           \
        int row = wc * 64 + j * 16 + fr;                                      \
        int off = row * 128 + ((kk2 * 64 + fg * 16) ^ VSWZ(row));             \
        vf[j] = *(const v8s*)(VtB + off);                                     \
      }                                                                       \
      _Pragma("unroll")                                                       \
      for (int i = 0; i < 2; i++)                                             \
        _Pragma("unroll")                                                     \
        for (int j = 0; j < 4; j++)                                           \
          oacc[i][j] = __builtin_amdgcn_mfma_f32_16x16x32_bf16(               \
              pf[i], vf[j], oacc[i][j], 0, 0, 0);                             \
    }                                                                         \
    __builtin_amdgcn_s_setprio(0);                                            \
    __syncthreads();                                                          \
  }

  for (int tp = 0; tp < 16; tp++) {
    int kt = tp * 128;
    ATTN_TILE(kt, Ks1, Ks0, vA, vB, true);
    ATTN_TILE(kt + 64, Ks0, Ks1, vB, vA, (tp < 15));
  }
#undef ATTN_TILE

  // ---- normalize + store ----
#pragma unroll
  for (int i = 0; i < 2; i++)
#pragma unroll
    for (int r = 0; r < 4; r++) {
      int qrow = wr * 32 + i * 16 + fg * 4 + r;
      float linv = 1.f / (Lp[qrow] + Lp[64 + qrow]);
#pragma unroll
      for (int j = 0; j < 4; j++) {
        int d = wc * 64 + j * 16 + fr;
        o[base + (size_t)(q0 + qrow) * HD + d] = f2b(oacc[i][j][r] * linv);
      }
    }
}

// ------------------------------------------------------------------
// Orchestration. Inputs f32, output f32, intermediates bf16.
// ------------------------------------------------------------------
extern "C" void kernel_launch(void* const* d_in, const int* in_sizes, int n_in,
                              void* d_out, int out_size, void* d_ws, size_t ws_size,
                              hipStream_t stream) {
  (void)in_sizes; (void)n_in; (void)out_size;
  const float* x    = (const float*)d_in[0];
  const float* fcos = (const float*)d_in[1];
  const float* fsin = (const float*)d_in[2];
  const float* wq   = (const float*)d_in[3];
  const float* wk   = (const float*)d_in[4];
  const float* wv   = (const float*)d_in[5];
  const float* nqw  = (const float*)d_in[6];
  const float* nqb  = (const float*)d_in[7];
  const float* nkw  = (const float*)d_in[8];
  const float* nkb  = (const float*)d_in[9];
  const float* wo   = (const float*)d_in[10];
  const float* bo   = (const float*)d_in[11];
  const float* ln1w = (const float*)d_in[12];
  const float* ln1b = (const float*)d_in[13];
  const float* ln3w = (const float*)d_in[14];
  const float* ln3b = (const float*)d_in[15];
  const float* w1   = (const float*)d_in[16];
  const float* b1   = (const float*)d_in[17];
  const float* w2   = (const float*)d_in[18];
  const float* b2   = (const float*)d_in[19];
  float* out = (float*)d_out;

  const size_t SEG = (size_t)4096 * 2048;  // 8M bf16 = 16 MB
  bf16* base = (bf16*)d_ws;
  bf16* q        = base + 0 * SEG;
  bf16* k        = base + 1 * SEG;
  bf16* v        = base + 2 * SEG;
  bf16* n1       = base + 3 * SEG;
  bf16* attn_out = base + 3 * SEG;
  bf16* x2       = base + 4 * SEG;
  bf16* n3       = base + 5 * SEG;
  bf16* h        = base + 0 * SEG;  // 64MB overlays q/k/v/attn_out

  dim3 blk(256);
  ln2048_kernel<float><<<4096, blk, 0, stream>>>(x, ln1w, ln1b, n1);

  bool mfma_path = ws_size >= (size_t)128 * 1024 * 1024;
  if (mfma_path) {
    bf16* W = base + 6 * SEG;            // 32MB weight area
    bf16* wqT = W;                       // wq/wk/wvT contiguous -> fused BT
    bf16* wkT = W + 4 * 1024 * 1024;
    bf16* wvT = W + 8 * 1024 * 1024;
    bf16* woT = W;
    bf16* w1T = W;
    bf16* w2T = W;

    dim3 cg22(32, 32);
    dim3 g16(16, 32);
    dim3 g48(48, 32);                    // fused QKV: N=6144
    dim3 g64(64, 32);

    convT_kernel<<<cg22, blk, 0, stream>>>(wq, wqT, 2048, 2048);
    convT_kernel<<<cg22, blk, 0, stream>>>(wk, wkT, 2048, 2048);
    convT_kernel<<<cg22, blk, 0, stream>>>(wv, wvT, 2048, 2048);
    // fused QKV: BT rows 0-2047 = wqT, 2048-4095 = wkT, 4096-6143 = wvT;
    // output segment n>>11 selects q/k/v (SEG-strided, contiguous).
    mfma_gemm_kernel<0, float, bf16><<<g48, blk, 0, stream>>>(n1, wqT, q, nullptr, nullptr, 4096, 6144, 2048, 11, SEG);
    headln_rope_kernel<<<32768, blk, 0, stream>>>(q, k, nqw, nqb, nkw, nkb, fcos, fsin);
    attn_kernel<<<1024, blk, 0, stream>>>(q, k, v, attn_out);
    convT_kernel<<<cg22, blk, 0, stream>>>(wo, woT, 2048, 2048);
    mfma_gemm_kernel<1, float, bf16><<<g16, blk, 0, stream>>>(attn_out, woT, x2, bo, x, 4096, 2048, 2048, 11, 0);
    ln2048_kernel<bf16><<<4096, blk, 0, stream>>>(x2, ln3w, ln3b, n3);
    convT_kernel<<<dim3(128, 32), blk, 0, stream>>>(w1, w1T, 2048, 8192);
    mfma_gemm_kernel<2, float, bf16><<<g64, blk, 0, stream>>>(n3, w1T, h, b1, nullptr, 4096, 8192, 2048, 13, 0);
    convT_kernel<<<dim3(32, 128), blk, 0, stream>>>(w2, w2T, 8192, 2048);
    mfma_gemm_kernel<1, bf16, float><<<g16, blk, 0, stream>>>(h, w2T, out, b2, x2, 4096, 2048, 8192, 11, 0);
  } else {
    dim3 g2048(32, 64), g8192(128, 64);
    gemm_kernel<0, float, bf16><<<g2048, blk, 0, stream>>>(n1, wq, q, nullptr, nullptr, 4096, 2048, 2048);
    gemm_kernel<0, float, bf16><<<g2048, blk, 0, stream>>>(n1, wk, k, nullptr, nullptr, 4096, 2048, 2048);
    gemm_kernel<0, float, bf16><<<g2048, blk, 0, stream>>>(n1, wv, v, nullptr, nullptr, 4096, 2048, 2048);
    headln_rope_kernel<<<32768, blk, 0, stream>>>(q, k, nqw, nqb, nkw, nkb, fcos, fsin);
    attn_kernel<<<1024, blk, 0, stream>>>(q, k, v, attn_out);
    gemm_kernel<1, float, bf16><<<g2048, blk, 0, stream>>>(attn_out, wo, x2, bo, x, 4096, 2048, 2048);
    ln2048_kernel<bf16><<<4096, blk, 0, stream>>>(x2, ln3w, ln3b, n3);
    gemm_kernel<2, float, bf16><<<g8192, blk, 0, stream>>>(n3, w1, h, b1, nullptr, 4096, 8192, 2048);
    gemm_kernel<1, bf16, float><<<g2048, blk, 0, stream>>>(h, w2, out, b2, x2, 4096, 2048, 8192);
  }
}

// Round 6
// 990.301 us; speedup vs baseline: 1.1360x; 1.0276x over previous
//
#include <hip/hip_runtime.h>
#include <hip/hip_bf16.h>
#include <stdint.h>

typedef __hip_bfloat16 bf16;
typedef float v4f __attribute__((ext_vector_type(4)));
typedef short v8s __attribute__((ext_vector_type(8)));

#define DEV __device__ __forceinline__

DEV float b2f(bf16 x) { return __bfloat162float(x); }
DEV bf16 f2b(float x) { return __float2bfloat16(x); }

// dtype-polymorphic loaders/stores (global <-> f32 registers)
DEV void load4(const float* p, float* f) {
  float4 t = *(const float4*)p;
  f[0] = t.x; f[1] = t.y; f[2] = t.z; f[3] = t.w;
}
DEV void load4(const bf16* p, float* f) {
  union { uint2 u; bf16 h[4]; } t;
  t.u = *(const uint2*)p;
#pragma unroll
  for (int i = 0; i < 4; i++) f[i] = b2f(t.h[i]);
}
DEV void load8(const float* p, float* f) {
  float4 a = ((const float4*)p)[0], b = ((const float4*)p)[1];
  f[0] = a.x; f[1] = a.y; f[2] = a.z; f[3] = a.w;
  f[4] = b.x; f[5] = b.y; f[6] = b.z; f[7] = b.w;
}
DEV void load8(const bf16* p, float* f) {
  union { uint4 u; bf16 h[8]; } t;
  t.u = *(const uint4*)p;
#pragma unroll
  for (int i = 0; i < 8; i++) f[i] = b2f(t.h[i]);
}
DEV void store4(bf16* p, const float* f) {
  union { uint2 u; bf16 h[4]; } t;
#pragma unroll
  for (int i = 0; i < 4; i++) t.h[i] = f2b(f[i]);
  *(uint2*)p = t.u;
}
DEV void store4(float* p, const float* f) {
  *(float4*)p = make_float4(f[0], f[1], f[2], f[3]);
}

// async global->LDS, 16B per lane. LDS dest = wave-uniform base + lane*16.
DEV void gld_lds16(const bf16* g, bf16* l) {
  auto gp = reinterpret_cast<const __attribute__((address_space(1))) uint32_t*>(
      reinterpret_cast<uintptr_t>(g));
  auto lp = reinterpret_cast<__attribute__((address_space(3))) uint32_t*>(
      reinterpret_cast<uintptr_t>(l));
  __builtin_amdgcn_global_load_lds(gp, lp, 16, 0, 0);
}

// ------------------------------------------------------------------
// LayerNorm over 2048 columns. One block (256 thr) per row.
// ------------------------------------------------------------------
template <typename XT>
__global__ __launch_bounds__(256)
void ln2048_kernel(const XT* __restrict__ x, const float* __restrict__ w,
                   const float* __restrict__ b, bf16* __restrict__ y) {
  const int N = 2048;
  int row = blockIdx.x, tid = threadIdx.x;
  const XT* xr = x + (size_t)row * N;
  bf16* yr = y + (size_t)row * N;
  float f[8], s = 0.f, ss = 0.f;
  load8(xr + tid * 8, f);
#pragma unroll
  for (int i = 0; i < 8; i++) { s += f[i]; ss += f[i] * f[i]; }
#pragma unroll
  for (int off = 32; off >= 1; off >>= 1) {
    s  += __shfl_xor(s, off, 64);
    ss += __shfl_xor(ss, off, 64);
  }
  __shared__ float red0[4], red1[4];
  int wv = tid >> 6;
  if ((tid & 63) == 0) { red0[wv] = s; red1[wv] = ss; }
  __syncthreads();
  s  = red0[0] + red0[1] + red0[2] + red0[3];
  ss = red1[0] + red1[1] + red1[2] + red1[3];
  float mean = s * (1.f / N);
  float var  = ss * (1.f / N) - mean * mean;
  float inv  = rsqrtf(var + 1e-5f);
  float wf[8], bf_[8];
  load8(w + tid * 8, wf);
  load8(b + tid * 8, bf_);
  union { uint4 u; bf16 h[8]; } vo;
#pragma unroll
  for (int i = 0; i < 8; i++)
    vo.h[i] = f2b((f[i] - mean) * inv * wf[i] + bf_[i]);
  ((uint4*)yr)[tid] = vo.u;
}

// ------------------------------------------------------------------
// Per-head LayerNorm (DH=128) + RoPE, in place on bf16 q AND k in one
// launch (grid 32768: first half q/nq*, second half k/nk*).
// ------------------------------------------------------------------
__global__ __launch_bounds__(256)
void headln_rope_kernel(bf16* __restrict__ qb, bf16* __restrict__ kb,
                        const float* __restrict__ nqw, const float* __restrict__ nqb,
                        const float* __restrict__ nkw, const float* __restrict__ nkb,
                        const float* __restrict__ fcos, const float* __restrict__ fsin) {
  int bid = blockIdx.x;
  bf16* qk; const float* w; const float* b;
  if (bid < 16384) { qk = qb; w = nqw; b = nqb; }
  else             { qk = kb; w = nkw; b = nkb; bid -= 16384; }
  int tid = threadIdx.x;
  int wv = tid >> 6, ln = tid & 63;
  int idx = bid * 4 + wv;
  int row = idx >> 4, h = idx & 15;
  int srow = row & 2047;
  bf16* p = qk + (size_t)row * 2048 + h * 128 + ln * 2;
  union { unsigned int u; bf16 h2[2]; } v;
  v.u = *(const unsigned int*)p;
  float x0 = b2f(v.h2[0]), x1 = b2f(v.h2[1]);
  float s = x0 + x1, ss = x0 * x0 + x1 * x1;
#pragma unroll
  for (int off = 32; off >= 1; off >>= 1) {
    s  += __shfl_xor(s, off, 64);
    ss += __shfl_xor(ss, off, 64);
  }
  float mean = s * (1.f / 128.f);
  float var  = ss * (1.f / 128.f) - mean * mean;
  float inv  = rsqrtf(var + 1e-5f);
  float w0 = w[ln * 2], w1 = w[ln * 2 + 1];
  float b0 = b[ln * 2], b1 = b[ln * 2 + 1];
  x0 = (x0 - mean) * inv * w0 + b0;
  x1 = (x1 - mean) * inv * w1 + b1;
  float c  = fcos[srow * 64 + ln];
  float sn = fsin[srow * 64 + ln];
  v.h2[0] = f2b(x0 * c - x1 * sn);
  v.h2[1] = f2b(x0 * sn + x1 * c);
  *(unsigned int*)p = v.u;
}

// ------------------------------------------------------------------
// Weight convert+transpose: src f32 [K][N] -> dst bf16 [N][K].
// ------------------------------------------------------------------
__global__ __launch_bounds__(256)
void convT_kernel(const float* __restrict__ src, bf16* __restrict__ dst,
                  int K, int N) {
  __shared__ float T[64][65];
  int n0 = blockIdx.x * 64, k0 = blockIdx.y * 64;
  int t = threadIdx.x;
  int tr = t >> 4, tc4 = (t & 15) * 4;
#pragma unroll
  for (int it = 0; it < 4; it++) {
    float4 v = *(const float4*)&src[(size_t)(k0 + tr + 16 * it) * N + n0 + tc4];
    T[tr + 16 * it][tc4 + 0] = v.x;
    T[tr + 16 * it][tc4 + 1] = v.y;
    T[tr + 16 * it][tc4 + 2] = v.z;
    T[tr + 16 * it][tc4 + 3] = v.w;
  }
  __syncthreads();
#pragma unroll
  for (int it = 0; it < 4; it++) {
    int n = tr + 16 * it;
    union { uint2 u; bf16 h[4]; } o;
#pragma unroll
    for (int c = 0; c < 4; c++) o.h[c] = f2b(T[tc4 + c][n]);
    *(uint2*)&dst[(size_t)(n0 + n) * K + k0 + tc4] = o.u;
  }
}

// ------------------------------------------------------------------
// MFMA bt-GEMM: C = A * BT^T.  R6: BK=64 (two [128][32] sub-buffers
// per operand; hi-half source = lo source + 32 k) so barrier/vmcnt
// drains per K halve vs the R5 BK=32 loop (MfmaUtil 24%, VALU 26%,
// both pipes idle -> drain-bound). Staging dest formula and fragment
// layout are byte-identical to the verified BK=32 path.
// R6b: bf16 outputs go through an LDS-staged epilogue (chunk^row
// swizzled [128][128] bf16 in the freed 32KB stage buffer) and are
// stored as row-contiguous uint4 -> full 64B lines (R5 counter: bf16
// direct stores gave 32B segments, WRITE_SIZE 2x output = 127MB).
// XCD-chunk swizzle (T1) + segmented epilogue addressing:
//   C[(n>>ldc_log2)*seg_stride + (m<<ldc_log2) + (n&(ldc-1))]
// ------------------------------------------------------------------
template <int EPI, typename RT, typename OT>
__global__ __launch_bounds__(256, 2)
void mfma_gemm_kernel(const bf16* __restrict__ A, const bf16* __restrict__ BT,
                      OT* __restrict__ C, const float* __restrict__ bias,
                      const RT* __restrict__ res, int M, int N, int K,
                      int ldc_log2, size_t seg_stride) {
  __shared__ __align__(16) char smem[32768];
  bf16* As_lo = (bf16*)smem;           // [128][32] each, 8KB
  bf16* As_hi = As_lo + 4096;
  bf16* Bs_lo = As_lo + 8192;
  bf16* Bs_hi = As_lo + 12288;
  int tid = threadIdx.x;
  int lane = tid & 63, wave = tid >> 6;
  int wr = wave >> 1, wc = wave & 1;

  // XCD swizzle (all grids have nwg % 8 == 0)
  int nbx = gridDim.x;
  int bid = blockIdx.y * nbx + blockIdx.x;
  int nwg = nbx * gridDim.y;
  int cpx = nwg >> 3;
  int swz = (bid & 7) * cpx + (bid >> 3);
  int m0 = (swz / nbx) * 128, n0 = (swz % nbx) * 128;

  int ls_row = lane >> 2;          // 0..15
  int ls_k   = (lane & 3) * 8;     // 0,8,16,24
  int t0 = 2 * wave, t1 = 2 * wave + 1;
  const bf16* gA0 = A  + (size_t)(m0 + 16 * t0 + ls_row) * K + ls_k;
  const bf16* gA1 = A  + (size_t)(m0 + 16 * t1 + ls_row) * K + ls_k;
  const bf16* gB0 = BT + (size_t)(n0 + 16 * t0 + ls_row) * K + ls_k;
  const bf16* gB1 = BT + (size_t)(n0 + 16 * t1 + ls_row) * K + ls_k;
  bf16* lA0lo = As_lo + t0 * 512;  bf16* lA1lo = As_lo + t1 * 512;
  bf16* lA0hi = As_hi + t0 * 512;  bf16* lA1hi = As_hi + t1 * 512;
  bf16* lB0lo = Bs_lo + t0 * 512;  bf16* lB1lo = Bs_lo + t1 * 512;
  bf16* lB0hi = Bs_hi + t0 * 512;  bf16* lB1hi = Bs_hi + t1 * 512;

  int fr = lane & 15, fk = (lane >> 4) * 8;
  int fA = (wr * 64 + fr) * 32 + fk;
  int fB = (wc * 64 + fr) * 32 + fk;

  v4f acc[4][4];
#pragma unroll
  for (int i = 0; i < 4; i++)
#pragma unroll
    for (int j = 0; j < 4; j++) acc[i][j] = (v4f){0.f, 0.f, 0.f, 0.f};

  for (int k0 = 0; k0 < K; k0 += 64) {
    __syncthreads();
    gld_lds16(gA0,      lA0lo); gld_lds16(gA1,      lA1lo);
    gld_lds16(gA0 + 32, lA0hi); gld_lds16(gA1 + 32, lA1hi);
    gld_lds16(gB0,      lB0lo); gld_lds16(gB1,      lB1lo);
    gld_lds16(gB0 + 32, lB0hi); gld_lds16(gB1 + 32, lB1hi);
    gA0 += 64; gA1 += 64; gB0 += 64; gB1 += 64;
    __syncthreads();
    {
      v8s af[4], bfr[4];
#pragma unroll
      for (int i = 0; i < 4; i++) af[i]  = *(const v8s*)(As_lo + fA + i * 512);
#pragma unroll
      for (int j = 0; j < 4; j++) bfr[j] = *(const v8s*)(Bs_lo + fB + j * 512);
#pragma unroll
      for (int i = 0; i < 4; i++)
#pragma unroll
        for (int j = 0; j < 4; j++)
          acc[i][j] = __builtin_amdgcn_mfma_f32_16x16x32_bf16(af[i], bfr[j],
                                                              acc[i][j], 0, 0, 0);
    }
    {
      v8s af[4], bfr[4];
#pragma unroll
      for (int i = 0; i < 4; i++) af[i]  = *(const v8s*)(As_hi + fA + i * 512);
#pragma unroll
      for (int j = 0; j < 4; j++) bfr[j] = *(const v8s*)(Bs_hi + fB + j * 512);
#pragma unroll
      for (int i = 0; i < 4; i++)
#pragma unroll
        for (int j = 0; j < 4; j++)
          acc[i][j] = __builtin_amdgcn_mfma_f32_16x16x32_bf16(af[i], bfr[j],
                                                              acc[i][j], 0, 0, 0);
    }
  }

  int rq = (lane >> 4) * 4;
  int ldm = 1 << ldc_log2;
  if constexpr (__is_same(OT, float)) {
    // f32 outputs: 16 lanes x 4B = full 64B lines already.
#pragma unroll
    for (int j = 0; j < 4; j++) {
      int n = n0 + wc * 64 + j * 16 + fr;
      float bb = (EPI >= 1) ? bias[n] : 0.f;
      size_t cseg = (size_t)(n >> ldc_log2) * seg_stride + (n & (ldm - 1));
#pragma unroll
      for (int i = 0; i < 4; i++) {
#pragma unroll
        for (int r = 0; r < 4; r++) {
          int m = m0 + wr * 64 + i * 16 + rq + r;
          float val = acc[i][j][r] + bb;
          if (EPI == 2)
            val = 0.5f * val * (1.f + erff(val * 0.70710678118654752f));
          if (EPI == 1) {
            if constexpr (__is_same(RT, float)) val += res[(size_t)m * N + n];
            else                                val += b2f(res[(size_t)m * N + n]);
          }
          C[cseg + ((size_t)m << ldc_log2)] = val;
        }
      }
    }
  } else {
    // bf16 outputs: stage tile in LDS (chunk^row swizzle, exactly 32KB),
    // then row-contiguous uint4 stores (full cachelines).
    __syncthreads();  // all frag ds_reads done; stage buffers reusable
#pragma unroll
    for (int j = 0; j < 4; j++) {
      int col = wc * 64 + j * 16 + fr;
      int n = n0 + col;
      float bb = (EPI >= 1) ? bias[n] : 0.f;
#pragma unroll
      for (int i = 0; i < 4; i++) {
#pragma unroll
        for (int r = 0; r < 4; r++) {
          int m = m0 + wr * 64 + i * 16 + rq + r;
          float val = acc[i][j][r] + bb;
          if (EPI == 2)
            val = 0.5f * val * (1.f + erff(val * 0.70710678118654752f));
          if (EPI == 1) {
            if constexpr (__is_same(RT, float)) val += res[(size_t)m * N + n];
            else                                val += b2f(res[(size_t)m * N + n]);
          }
          int row = wr * 64 + i * 16 + rq + r;
          int byteoff = row * 256 + ((((col >> 3) ^ (row & 7))) << 4) + ((col & 7) << 1);
          *(bf16*)(smem + byteoff) = f2b(val);
        }
      }
    }
    __syncthreads();
    int row = tid >> 1, half = tid & 1;
    size_t gm = (size_t)(m0 + row) << ldc_log2;
#pragma unroll
    for (int it = 0; it < 8; it++) {
      int coln = half * 64 + it * 8;
      int n = n0 + coln;
      size_t cseg = (size_t)(n >> ldc_log2) * seg_stride + (n & (ldm - 1));
      uint4 val = *(uint4*)(smem + row * 256 + ((((coln >> 3) ^ (row & 7))) << 4));
      *(uint4*)&C[cseg + gm] = val;
    }
  }
}

// ------------------------------------------------------------------
// Fallback vector GEMM (round-3 proven path, used if ws too small).
// ------------------------------------------------------------------
template <int EPI, typename RT, typename OT>
__global__ __launch_bounds__(256)
void gemm_kernel(const bf16* __restrict__ A, const float* __restrict__ Bm,
                 OT* __restrict__ C, const float* __restrict__ bias,
                 const RT* __restrict__ res, int M, int N, int K) {
  const int BK = 32;
  __shared__ __align__(16) float As[BK][68];
  __shared__ __align__(16) float Bs[BK][68];
  int tid = threadIdx.x;
  int bm = blockIdx.y, bn = blockIdx.x;
  int tx = tid & 15, ty = tid >> 4;
  int am = tid >> 2, ak8 = (tid & 3) * 8;
  int bkr = tid >> 3, bn8 = (tid & 7) * 8;
  const bf16* Aptr = A + (size_t)(bm * 64 + am) * K + ak8;
  const float* Bptr = Bm + (size_t)bkr * N + bn * 64 + bn8;
  float acc[4][4] = {};
  for (int k0 = 0; k0 < K; k0 += BK) {
    float av[8], bv[8];
    load8(Aptr, av);
    load8(Bptr, bv);
    __syncthreads();
#pragma unroll
    for (int j = 0; j < 8; j++) As[ak8 + j][am] = av[j];
#pragma unroll
    for (int j = 0; j < 8; j++) Bs[bkr][bn8 + j] = bv[j];
    __syncthreads();
    Aptr += BK;
    Bptr += (size_t)BK * N;
#pragma unroll 8
    for (int kk = 0; kk < BK; kk++) {
      float a0[4], b0[4];
      *(float4*)a0 = *(const float4*)&As[kk][ty * 4];
      *(float4*)b0 = *(const float4*)&Bs[kk][tx * 4];
#pragma unroll
      for (int i = 0; i < 4; i++)
#pragma unroll
        for (int j = 0; j < 4; j++)
          acc[i][j] += a0[i] * b0[j];
    }
  }
  int m0 = bm * 64 + ty * 4, n0 = bn * 64 + tx * 4;
#pragma unroll
  for (int i = 0; i < 4; i++) {
    float r4[4];
#pragma unroll
    for (int j = 0; j < 4; j++) r4[j] = acc[i][j];
    if (EPI >= 1) {
      float bb[4];
      load4(bias + n0, bb);
#pragma unroll
      for (int j = 0; j < 4; j++) r4[j] += bb[j];
    }
    if (EPI == 2) {
#pragma unroll
      for (int j = 0; j < 4; j++)
        r4[j] = 0.5f * r4[j] * (1.f + erff(r4[j] * 0.70710678118654752f));
    }
    if (EPI == 1) {
      float rr[4];
      load4(res + (size_t)(m0 + i) * N + n0, rr);
#pragma unroll
      for (int j = 0; j < 4; j++) r4[j] += rr[j];
    }
    store4(&C[(size_t)(m0 + i) * N + n0], r4);
  }
}

// ------------------------------------------------------------------
// MFMA flash-style attention, PIPELINED (R3-verified version, QBLK=64).
// 256 thr = 4 waves (2x2), Q-tile 64, KV-tile 64, DH=128.
// K double-buffered in LDS (gld_lds ping-pong), V prefetched to regs
// (T14 issue-early/write-late), both issued BEFORE QK^T so the L2
// latency hides under QK^T+softmax. 2 barriers/tile, statically
// unrolled 2-tile body. R4's QBLK=128 spilled (~160 persistent VGPRs,
// WRITE_SIZE 16->49MB scratch) and regressed 282us — reverted.
// LDS: K 2x16K + Vt 16K + P 8K + Lp 0.5K = 56.5KB -> 2 blocks/CU.
// ------------------------------------------------------------------
#define VSWZ(r) (((((r) >> 3) ^ (r)) & 7) << 4)

__global__ __launch_bounds__(256, 2)
void attn_kernel(const bf16* __restrict__ q, const bf16* __restrict__ k,
                 const bf16* __restrict__ v, bf16* __restrict__ o) {
  const int S = 2048, HD = 2048;
  __shared__ __align__(16) char smem[57856];
  char* Ks0 = smem;                    // K ping [64][128]bf16, 256B rows
  char* Ks1 = smem + 16384;            // K pong
  char* VtB = smem + 32768;            // V^T [128][64]bf16, 128B rows
  char* PB  = smem + 49152;            // P [64][64]bf16, 128B rows
  float* Lp = (float*)(smem + 57344);  // [2][64]

  // bijective XCD-chunk swizzle: 1024 blocks, 8 XCDs, 128 each.
  int id = blockIdx.x;
  int swzb = (id & 7) * 128 + (id >> 3);
  int bh = swzb >> 5, qb = swzb & 31;
  int q0 = qb * 64;
  size_t base = (size_t)(bh >> 4) * S * HD + (size_t)(bh & 15) * 128;

  int tid = threadIdx.x;
  int lane = tid & 63, wave = tid >> 6;
  int wr = wave >> 1, wc = wave & 1;
  int fr = lane & 15, fg = lane >> 4;

  if (tid < 128) Lp[tid] = 0.f;

  union V4U { uint4 u; bf16 h[8]; };
  int vr0 = (tid & 15) * 4, vd0 = (tid >> 4) * 8;

  // ---- prologue: Q -> Ks0, K tile0 -> Ks1, V tile0 -> regs ----
#pragma unroll
  for (int t = 0; t < 4; t++) {
    int ti = wave * 4 + t;
    int r = ti * 4 + fg;
    int cb = (fr * 16) ^ ((r & 7) << 4);
    gld_lds16(q + base + (size_t)(q0 + r) * HD + (cb >> 1), (bf16*)Ks0 + ti * 512);
    gld_lds16(k + base + (size_t)r * HD + (cb >> 1), (bf16*)Ks1 + ti * 512);
  }
  V4U vA[4], vB[4];
#pragma unroll
  for (int j = 0; j < 4; j++)
    vA[j].u = *(const uint4*)&v[base + (size_t)(vr0 + j) * HD + vd0];
  __syncthreads();  // Q + K0 in LDS, V0 in regs

  v8s qfrag[2][4];
#pragma unroll
  for (int i = 0; i < 2; i++)
#pragma unroll
    for (int kk = 0; kk < 4; kk++) {
      int row = wr * 32 + i * 16 + fr;
      int off = row * 256 + ((kk * 64 + fg * 16) ^ ((row & 7) << 4));
      qfrag[i][kk] = *(const v8s*)(Ks0 + off);
    }
  __syncthreads();  // all waves done reading Q before tile0 stages into Ks0

  v4f oacc[2][4];
#pragma unroll
  for (int i = 0; i < 2; i++)
#pragma unroll
    for (int j = 0; j < 4; j++) oacc[i][j] = (v4f){0.f, 0.f, 0.f, 0.f};

  const float scale = 0.08838834764831845f;

  // Per-tile body. Hazards: (a) Vt write guarded by prev tile's end
  // barrier; (b) KNXT staging guarded by prev tile's barriers (last
  // reader was QK^T of tile t-1); V regs drained by the mid barrier.
#define ATTN_TILE(KT, KCUR, KNXT, VCUR, VNXT, STAGE_NEXT)                     \
  {                                                                           \
    _Pragma("unroll")                                                         \
    for (int c = 0; c < 8; c++) {                                             \
      int d = vd0 + c;                                                        \
      union { uint2 u2; bf16 hh[4]; } pk;                                     \
      _Pragma("unroll")                                                       \
      for (int j = 0; j < 4; j++) pk.hh[j] = VCUR[j].h[c];                    \
      *(uint2*)(VtB + d * 128 + ((vr0 * 2) ^ VSWZ(d))) = pk.u2;               \
    }                                                                         \
    if (STAGE_NEXT) {                                                         \
      _Pragma("unroll")                                                       \
      for (int t = 0; t < 4; t++) {                                           \
        int ti = wave * 4 + t;                                                \
        int r = ti * 4 + fg;                                                  \
        int cb = (fr * 16) ^ ((r & 7) << 4);                                  \
        gld_lds16(k + base + (size_t)((KT) + 64 + r) * HD + (cb >> 1),        \
                  (bf16*)(KNXT) + ti * 512);                                  \
      }                                                                       \
      _Pragma("unroll")                                                       \
      for (int j = 0; j < 4; j++)                                             \
        VNXT[j].u =                                                           \
            *(const uint4*)&v[base + (size_t)((KT) + 64 + vr0 + j) * HD + vd0]; \
    }                                                                         \
    v4f sacc[2][2];                                                           \
    _Pragma("unroll")                                                         \
    for (int i = 0; i < 2; i++)                                               \
      _Pragma("unroll")                                                       \
      for (int j = 0; j < 2; j++) sacc[i][j] = (v4f){0.f, 0.f, 0.f, 0.f};     \
    __builtin_amdgcn_s_setprio(1);                                            \
    _Pragma("unroll")                                                         \
    for (int kk = 0; kk < 4; kk++) {                                          \
      v8s kf[2];                                                              \
      _Pragma("unroll")                                                       \
      for (int j = 0; j < 2; j++) {                                           \
        int row = wc * 32 + j * 16 + fr;                                      \
        int off = row * 256 + ((kk * 64 + fg * 16) ^ ((row & 7) << 4));       \
        kf[j] = *(const v8s*)((KCUR) + off);                                  \
      }                                                                       \
      _Pragma("unroll")                                                       \
      for (int i = 0; i < 2; i++)                                             \
        _Pragma("unroll")                                                     \
        for (int j = 0; j < 2; j++)                                           \
          sacc[i][j] = __builtin_amdgcn_mfma_f32_16x16x32_bf16(               \
              qfrag[i][kk], kf[j], sacc[i][j], 0, 0, 0);                      \
    }                                                                         \
    __builtin_amdgcn_s_setprio(0);                                            \
    _Pragma("unroll")                                                         \
    for (int i = 0; i < 2; i++)                                               \
      _Pragma("unroll")                                                       \
      for (int r = 0; r < 4; r++) {                                           \
        int qrow = wr * 32 + i * 16 + fg * 4 + r;                             \
        float e0 = __expf(sacc[i][0][r] * scale);                             \
        float e1 = __expf(sacc[i][1][r] * scale);                             \
        int sw = VSWZ(qrow);                                                  \
        int c0 = wc * 64 + fr * 2;                                            \
        *(bf16*)(PB + qrow * 128 + (c0 ^ sw)) = f2b(e0);                      \
        *(bf16*)(PB + qrow * 128 + ((c0 + 32) ^ sw)) = f2b(e1);               \
        float s_ = e0 + e1;                                                   \
        s_ += __shfl_xor(s_, 1, 64);                                          \
        s_ += __shfl_xor(s_, 2, 64);                                          \
        s_ += __shfl_xor(s_, 4, 64);                                          \
        s_ += __shfl_xor(s_, 8, 64);                                          \
        if (fr == 0) Lp[wc * 64 + qrow] += s_;                                \
      }                                                                       \
    __syncthreads();                                                          \
    __builtin_amdgcn_s_setprio(1);                                            \
    _Pragma("unroll")                                                         \
    for (int kk2 = 0; kk2 < 2; kk2++) {                                       \
      v8s pf[2], vf[4];                                                       \
      _Pragma("unroll")                                                       \
      for (int i = 0; i < 2; i++) {                                           \
        int row = wr * 32 + i * 16 + fr;                                      \
        int off = row * 128 + ((kk2 * 64 + fg * 16) ^ VSWZ(row));             \
        pf[i] = *(const v8s*)(PB + off);                                      \
      }                                                                       \
      _Pragma("unroll")                                                       \
      for (int j = 0; j < 4; j++) {                                           \
        int row = wc * 64 + j * 16 + fr;                                      \
        int off = row * 128 + ((kk2 * 64 + fg * 16) ^ VSWZ(row));             \
        vf[j] = *(const v8s*)(VtB + off);                                     \
      }                                                                       \
      _Pragma("unroll")                                                       \
      for (int i = 0; i < 2; i++)                                             \
        _Pragma("unroll")                                                     \
        for (int j = 0; j < 4; j++)                                           \
          oacc[i][j] = __builtin_amdgcn_mfma_f32_16x16x32_bf16(               \
              pf[i], vf[j], oacc[i][j], 0, 0, 0);                             \
    }                                                                         \
    __builtin_amdgcn_s_setprio(0);                                            \
    __syncthreads();                                                          \
  }

  for (int tp = 0; tp < 16; tp++) {
    int kt = tp * 128;
    ATTN_TILE(kt, Ks1, Ks0, vA, vB, true);
    ATTN_TILE(kt + 64, Ks0, Ks1, vB, vA, (tp < 15));
  }
#undef ATTN_TILE

  // ---- normalize + store ----
#pragma unroll
  for (int i = 0; i < 2; i++)
#pragma unroll
    for (int r = 0; r < 4; r++) {
      int qrow = wr * 32 + i * 16 + fg * 4 + r;
      float linv = 1.f / (Lp[qrow] + Lp[64 + qrow]);
#pragma unroll
      for (int j = 0; j < 4; j++) {
        int d = wc * 64 + j * 16 + fr;
        o[base + (size_t)(q0 + qrow) * HD + d] = f2b(oacc[i][j][r] * linv);
      }
    }
}

// ------------------------------------------------------------------
// Orchestration. Inputs f32, output f32, intermediates bf16.
// ------------------------------------------------------------------
extern "C" void kernel_launch(void* const* d_in, const int* in_sizes, int n_in,
                              void* d_out, int out_size, void* d_ws, size_t ws_size,
                              hipStream_t stream) {
  (void)in_sizes; (void)n_in; (void)out_size;
  const float* x    = (const float*)d_in[0];
  const float* fcos = (const float*)d_in[1];
  const float* fsin = (const float*)d_in[2];
  const float* wq   = (const float*)d_in[3];
  const float* wk   = (const float*)d_in[4];
  const float* wv   = (const float*)d_in[5];
  const float* nqw  = (const float*)d_in[6];
  const float* nqb  = (const float*)d_in[7];
  const float* nkw  = (const float*)d_in[8];
  const float* nkb  = (const float*)d_in[9];
  const float* wo   = (const float*)d_in[10];
  const float* bo   = (const float*)d_in[11];
  const float* ln1w = (const float*)d_in[12];
  const float* ln1b = (const float*)d_in[13];
  const float* ln3w = (const float*)d_in[14];
  const float* ln3b = (const float*)d_in[15];
  const float* w1   = (const float*)d_in[16];
  const float* b1   = (const float*)d_in[17];
  const float* w2   = (const float*)d_in[18];
  const float* b2   = (const float*)d_in[19];
  float* out = (float*)d_out;

  const size_t SEG = (size_t)4096 * 2048;  // 8M bf16 = 16 MB
  bf16* base = (bf16*)d_ws;
  bf16* q        = base + 0 * SEG;
  bf16* k        = base + 1 * SEG;
  bf16* v        = base + 2 * SEG;
  bf16* n1       = base + 3 * SEG;
  bf16* attn_out = base + 3 * SEG;
  bf16* x2       = base + 4 * SEG;
  bf16* n3       = base + 5 * SEG;
  bf16* h        = base + 0 * SEG;  // 64MB overlays q/k/v/attn_out

  dim3 blk(256);
  ln2048_kernel<float><<<4096, blk, 0, stream>>>(x, ln1w, ln1b, n1);

  bool mfma_path = ws_size >= (size_t)128 * 1024 * 1024;
  if (mfma_path) {
    bf16* W = base + 6 * SEG;            // 32MB weight area
    bf16* wqT = W;                       // wq/wk/wvT contiguous -> fused BT
    bf16* wkT = W + 4 * 1024 * 1024;
    bf16* wvT = W + 8 * 1024 * 1024;
    bf16* woT = W;
    bf16* w1T = W;
    bf16* w2T = W;

    dim3 cg22(32, 32);
    dim3 g16(16, 32);
    dim3 g48(48, 32);                    // fused QKV: N=6144
    dim3 g64(64, 32);

    convT_kernel<<<cg22, blk, 0, stream>>>(wq, wqT, 2048, 2048);
    convT_kernel<<<cg22, blk, 0, stream>>>(wk, wkT, 2048, 2048);
    convT_kernel<<<cg22, blk, 0, stream>>>(wv, wvT, 2048, 2048);
    // fused QKV: BT rows 0-2047 = wqT, 2048-4095 = wkT, 4096-6143 = wvT;
    // output segment n>>11 selects q/k/v (SEG-strided, contiguous).
    mfma_gemm_kernel<0, float, bf16><<<g48, blk, 0, stream>>>(n1, wqT, q, nullptr, nullptr, 4096, 6144, 2048, 11, SEG);
    headln_rope_kernel<<<32768, blk, 0, stream>>>(q, k, nqw, nqb, nkw, nkb, fcos, fsin);
    attn_kernel<<<1024, blk, 0, stream>>>(q, k, v, attn_out);
    convT_kernel<<<cg22, blk, 0, stream>>>(wo, woT, 2048, 2048);
    mfma_gemm_kernel<1, float, bf16><<<g16, blk, 0, stream>>>(attn_out, woT, x2, bo, x, 4096, 2048, 2048, 11, 0);
    ln2048_kernel<bf16><<<4096, blk, 0, stream>>>(x2, ln3w, ln3b, n3);
    convT_kernel<<<dim3(128, 32), blk, 0, stream>>>(w1, w1T, 2048, 8192);
    mfma_gemm_kernel<2, float, bf16><<<g64, blk, 0, stream>>>(n3, w1T, h, b1, nullptr, 4096, 8192, 2048, 13, 0);
    convT_kernel<<<dim3(32, 128), blk, 0, stream>>>(w2, w2T, 8192, 2048);
    mfma_gemm_kernel<1, bf16, float><<<g16, blk, 0, stream>>>(h, w2T, out, b2, x2, 4096, 2048, 8192, 11, 0);
  } else {
    dim3 g2048(32, 64), g8192(128, 64);
    gemm_kernel<0, float, bf16><<<g2048, blk, 0, stream>>>(n1, wq, q, nullptr, nullptr, 4096, 2048, 2048);
    gemm_kernel<0, float, bf16><<<g2048, blk, 0, stream>>>(n1, wk, k, nullptr, nullptr, 4096, 2048, 2048);
    gemm_kernel<0, float, bf16><<<g2048, blk, 0, stream>>>(n1, wv, v, nullptr, nullptr, 4096, 2048, 2048);
    headln_rope_kernel<<<32768, blk, 0, stream>>>(q, k, nqw, nqb, nkw, nkb, fcos, fsin);
    attn_kernel<<<1024, blk, 0, stream>>>(q, k, v, attn_out);
    gemm_kernel<1, float, bf16><<<g2048, blk, 0, stream>>>(attn_out, wo, x2, bo, x, 4096, 2048, 2048);
    ln2048_kernel<bf16><<<4096, blk, 0, stream>>>(x2, ln3w, ln3b, n3);
    gemm_kernel<2, float, bf16><<<g8192, blk, 0, stream>>>(n3, w1, h, b1, nullptr, 4096, 8192, 2048);
    gemm_kernel<1, bf16, float><<<g2048, blk, 0, stream>>>(h, w2, out, b2, x2, 4096, 2048, 8192);
  }
}